// Round 7
// baseline (34.539 us; speedup 1.0000x reference)
//
#include <hip/hip_runtime.h>
#include <cstddef>

// out[e,j] = tanh( A[row[e],j] + B[col[e],j] )
// A[n] = W0·u + W1·v,  B[n] = W0·v + W1·u,  u = x[n,0:64]+x[n,128:192], v = x[n,64:128]
// Karatsuba: s = (W0+W1)/2·(u+v), d = (W0-W1)/2·(u-v)  =>  A = s+d, B = s-d.
// A/B tables: fp16, padded to 16 elements (32 B) per node.
// k1: each quad computes TWO nodes so every ws/wd ds_read_b128 feeds 16 FMAs
//     (halves LDS-pipe work per node — the modeled k1 bottleneck).
// k2: unchanged from round 6 (quad-cooperative gathers).

typedef float v4f __attribute__((ext_vector_type(4)));
typedef _Float16 v4h __attribute__((ext_vector_type(4)));

__device__ __forceinline__ float tanh_fast(float s) {
    // tanh(s) = 1 - 2/(e^{2s}+1);  e^{2s} = 2^(2*log2(e)*s). No clamp: inf/0 limits give +-1.
    float ex = __builtin_amdgcn_exp2f(s * 2.88539008f);
    return fmaf(-2.0f, __builtin_amdgcn_rcpf(ex + 1.0f), 1.0f);
}

// Kernel 1: 4 lanes (a quad) per TWO nodes; 128 nodes per 256-thread block.
__global__ __launch_bounds__(256) void node_proj_kernel(
    const float* __restrict__ x, const float* __restrict__ W,
    _Float16* __restrict__ A, _Float16* __restrict__ B, int nnodes)
{
    __shared__ float ws[9 * 64];   // (W0+W1)/2
    __shared__ float wd[9 * 64];   // (W0-W1)/2
    for (int k = threadIdx.x; k < 9 * 64; k += 256) {
        int j = k >> 6, c = k & 63;
        float w0 = W[j * 128 + c], w1 = W[j * 128 + 64 + c];
        ws[k] = 0.5f * (w0 + w1);
        wd[k] = 0.5f * (w0 - w1);
    }
    __syncthreads();

    const int quad = threadIdx.x >> 2;            // 0..63: node-pair within block
    const int q    = threadIdx.x & 3;             // lane within quad
    const int n0   = blockIdx.x * 128 + quad * 2;
    const int n1   = n0 + 1;
    if (n0 >= nnodes) return;
    const bool has1 = (n1 < nnodes);

    const float* xr0 = x + (size_t)n0 * 192;
    const float* xr1 = xr0 + 192;

    float ps0[9], pd0[9], ps1[9], pd1[9];
#pragma unroll
    for (int j = 0; j < 9; ++j) { ps0[j] = pd0[j] = ps1[j] = pd1[j] = 0.0f; }

#pragma unroll
    for (int ii = 0; ii < 4; ++ii) {
        const int c = 16 * ii + 4 * q;            // this lane's float4 channel offset
        v4f x0 = *(const v4f*)(xr0 + c);
        v4f x1 = *(const v4f*)(xr0 + 64 + c);
        v4f x2 = *(const v4f*)(xr0 + 128 + c);
        v4f u0  = x0 + x2;
        v4f su0 = u0 + x1, du0 = u0 - x1;

        v4f y0, y1, y2;
        if (has1) {
            y0 = *(const v4f*)(xr1 + c);
            y1 = *(const v4f*)(xr1 + 64 + c);
            y2 = *(const v4f*)(xr1 + 128 + c);
        } else {
            y0 = x0; y1 = x1; y2 = x2;            // dummy, result discarded
        }
        v4f u1  = y0 + y2;
        v4f su1 = u1 + y1, du1 = u1 - y1;

#pragma unroll
        for (int j = 0; j < 9; ++j) {
            v4f a = *(const v4f*)(ws + j * 64 + c);
            v4f b = *(const v4f*)(wd + j * 64 + c);
            ps0[j] = fmaf(a.x, su0.x, ps0[j]); ps0[j] = fmaf(a.y, su0.y, ps0[j]);
            ps0[j] = fmaf(a.z, su0.z, ps0[j]); ps0[j] = fmaf(a.w, su0.w, ps0[j]);
            pd0[j] = fmaf(b.x, du0.x, pd0[j]); pd0[j] = fmaf(b.y, du0.y, pd0[j]);
            pd0[j] = fmaf(b.z, du0.z, pd0[j]); pd0[j] = fmaf(b.w, du0.w, pd0[j]);
            ps1[j] = fmaf(a.x, su1.x, ps1[j]); ps1[j] = fmaf(a.y, su1.y, ps1[j]);
            ps1[j] = fmaf(a.z, su1.z, ps1[j]); ps1[j] = fmaf(a.w, su1.w, ps1[j]);
            pd1[j] = fmaf(b.x, du1.x, pd1[j]); pd1[j] = fmaf(b.y, du1.y, pd1[j]);
            pd1[j] = fmaf(b.z, du1.z, pd1[j]); pd1[j] = fmaf(b.w, du1.w, pd1[j]);
        }
    }

    // quad butterfly reduce (DPP, VALU-only): all 4 lanes get full 64-ch sums
#pragma unroll
    for (int j = 0; j < 9; ++j) {
        ps0[j] += __shfl_xor(ps0[j], 1); ps0[j] += __shfl_xor(ps0[j], 2);
        pd0[j] += __shfl_xor(pd0[j], 1); pd0[j] += __shfl_xor(pd0[j], 2);
        ps1[j] += __shfl_xor(ps1[j], 1); ps1[j] += __shfl_xor(ps1[j], 2);
        pd1[j] += __shfl_xor(pd1[j], 1); pd1[j] += __shfl_xor(pd1[j], 2);
    }

    _Float16* Ar = A + (size_t)n0 * 16;           // padded 32B records
    _Float16* Br = B + (size_t)n0 * 16;
    for (int j = q; j < 9; j += 4) {
        Ar[j] = (_Float16)(ps0[j] + pd0[j]);
        Br[j] = (_Float16)(ps0[j] - pd0[j]);
    }
    if (has1) {
        for (int j = q; j < 9; j += 4) {
            Ar[16 + j] = (_Float16)(ps1[j] + pd1[j]);
            Br[16 + j] = (_Float16)(ps1[j] - pd1[j]);
        }
    }
}

// Kernel 2 (unchanged from round 6): FOUR lanes per edge, quad-cooperative
// 8B-per-lane gathers of the 32B records; LDS transpose; coalesced v4f stores.
__global__ __launch_bounds__(256) void edge_map_kernel(
    const int* __restrict__ ei, const _Float16* __restrict__ A,
    const _Float16* __restrict__ B, float* __restrict__ out, int nedges)
{
    __shared__ float so[64 * 9];                  // 2.25 KB
    const int quad = threadIdx.x >> 2;            // 0..63: edge slot in block
    const int q    = threadIdx.x & 3;             // lane within quad
    const int e0   = blockIdx.x * 64;
    const int e    = e0 + quad;

    if (q < 3 && e < nedges) {                    // q==3 covers only pad -> masked off
        int row = ei[e];                          // 4-lane same-address: broadcast
        int col = ei[nedges + e];
        v4h a2 = *(const v4h*)(A + (size_t)row * 16 + 4 * q);
        v4h b2 = *(const v4h*)(B + (size_t)col * 16 + 4 * q);
        float* sl = so + quad * 9 + 4 * q;
#pragma unroll
        for (int i = 0; i < 4; ++i) {
            if (4 * q + i < 9)                    // q<2: all 4; q==2: only i==0
                sl[i] = tanh_fast((float)a2[i] + (float)b2[i]);
        }
    }
    __syncthreads();

    const int nval = (min(64, nedges - e0)) * 9;  // 576 for full blocks
    float* ob = out + (size_t)e0 * 9;
    int k4 = threadIdx.x * 4;
    if (k4 < nval) {
        if (k4 + 4 <= nval) {
            *(v4f*)(ob + k4) = *(const v4f*)(so + k4);   // 16B-aligned, coalesced
        } else {
            for (int m = k4; m < nval; ++m) ob[m] = so[m];
        }
    }
}

extern "C" void kernel_launch(void* const* d_in, const int* in_sizes, int n_in,
                              void* d_out, int out_size, void* d_ws, size_t ws_size,
                              hipStream_t stream) {
    const float* x  = (const float*)d_in[0];   // [N, 192] fp32
    const float* W  = (const float*)d_in[1];   // [9, 128] fp32
    const int*   ei = (const int*)d_in[2];     // [2, E] int32
    float* out = (float*)d_out;                // [E*9] fp32

    const int nnodes = in_sizes[0] / 192;
    const int nedges = in_sizes[2] / 2;

    _Float16* A = (_Float16*)d_ws;             // [nnodes*16] fp16 padded records
    _Float16* B = A + (size_t)nnodes * 16;     // [nnodes*16]

    const int blocks1 = (nnodes + 127) / 128;  // 128 nodes per block
    node_proj_kernel<<<blocks1, 256, 0, stream>>>(x, W, A, B, nnodes);

    const int blocks2 = (nedges + 63) / 64;    // 64 edges per 256-thread block
    edge_map_kernel<<<blocks2, 256, 0, stream>>>(ei, A, B, out, nedges);
}